// Round 1
// baseline (740.609 us; speedup 1.0000x reference)
//
#include <hip/hip_runtime.h>
#include <stdint.h>

typedef unsigned int uint;
typedef unsigned short ushort;

typedef float floatx4 __attribute__((ext_vector_type(4)));
typedef __bf16 bf16x8 __attribute__((ext_vector_type(8)));

// ---------- bf16 helpers (RNE, bit-level; avoids HIP API dependencies) ----------
__device__ __forceinline__ ushort f2bf(float f) {
  uint u = __float_as_uint(f);
  u += 0x7fffu + ((u >> 16) & 1u);
  return (ushort)(u >> 16);
}
__device__ __forceinline__ float bf2f(uint bits) {
  return __uint_as_float(bits << 16);
}

// ---------- cast x (f32) -> bf16 ----------
__global__ void k_cast_bf16(const float* __restrict__ in, ushort* __restrict__ out, int n4) {
  int i = blockIdx.x * blockDim.x + threadIdx.x;
  if (i >= n4) return;
  float4 v = reinterpret_cast<const float4*>(in)[i];
  ushort4 o;
  o.x = f2bf(v.x); o.y = f2bf(v.y); o.z = f2bf(v.z); o.w = f2bf(v.w);
  reinterpret_cast<ushort4*>(out)[i] = o;
}

// ---------- swizzle all 3 layers' [Wl;Wr] into MFMA B-fragment order ----------
// Wsw[l][kb*8+jt][lane][j] = Wcat[l][kb*32 + (lane>>4)*8 + j][jt*16 + (lane&15)]
__global__ void k_swizzle_w(const float* __restrict__ Wl0, const float* __restrict__ Wr0,
                            const float* __restrict__ Wl, const float* __restrict__ Wr,
                            ushort* __restrict__ Wsw) {
  int t = blockIdx.x * blockDim.x + threadIdx.x;
  if (t >= 3 * 64 * 64) return;
  int lane = t & 63;
  int blk = (t >> 6) & 63;      // kb*8 + jt
  int l = t >> 12;              // layer
  int kb = blk >> 3, jt = blk & 7;
  int col = jt * 16 + (lane & 15);
  ushort tmp[8];
#pragma unroll
  for (int j = 0; j < 8; ++j) {
    int k = kb * 32 + (lane >> 4) * 8 + j;
    float v;
    if (k < 128) {
      v = (l == 0) ? Wl0[k * 128 + col] : Wl[(l - 1) * 16384 + k * 128 + col];
    } else {
      int k2 = k - 128;
      v = (l == 0) ? Wr0[k2 * 128 + col] : Wr[(l - 1) * 16384 + k2 * 128 + col];
    }
    tmp[j] = f2bf(v);
  }
  reinterpret_cast<uint4*>(Wsw)[t] = *reinterpret_cast<uint4*>(tmp);
}

// ---------- degree histogram ----------
__global__ void k_deg(const int* __restrict__ dst, int* deg, int E) {
  int i = blockIdx.x * blockDim.x + threadIdx.x;
  int stride = gridDim.x * blockDim.x;
  for (; i < E; i += stride) atomicAdd(&deg[dst[i]], 1);
}

// ---------- scan pass A: per-1024-chunk exclusive scan + block sums ----------
__global__ void k_scan_a(const int* __restrict__ deg, int* __restrict__ partial,
                         int* __restrict__ blocksums, int n) {
  __shared__ int sm[256];
  int t = threadIdx.x;
  int base = blockIdx.x * 1024 + t * 4;
  int v0 = 0, v1 = 0, v2 = 0, v3 = 0;
  if (base + 0 < n) v0 = deg[base + 0];
  if (base + 1 < n) v1 = deg[base + 1];
  if (base + 2 < n) v2 = deg[base + 2];
  if (base + 3 < n) v3 = deg[base + 3];
  int mysum = v0 + v1 + v2 + v3;
  sm[t] = mysum;
  __syncthreads();
  for (int off = 1; off < 256; off <<= 1) {
    int x = (t >= off) ? sm[t - off] : 0;
    __syncthreads();
    sm[t] += x;
    __syncthreads();
  }
  int excl = sm[t] - mysum;
  if (t == 255) blocksums[blockIdx.x] = sm[255];
  if (base + 0 < n) partial[base + 0] = excl;
  if (base + 1 < n) partial[base + 1] = excl + v0;
  if (base + 2 < n) partial[base + 2] = excl + v0 + v1;
  if (base + 3 < n) partial[base + 3] = excl + v0 + v1 + v2;
}

// ---------- scan pass B: serial scan of block sums (~98 elements) ----------
__global__ void k_scan_b(int* blocksums, int nb) {
  if (threadIdx.x == 0 && blockIdx.x == 0) {
    int run = 0;
    for (int i = 0; i < nb; ++i) { int v = blocksums[i]; blocksums[i] = run; run += v; }
  }
}

// ---------- scan pass C: row_ptr, cursor copy, inv_deg ----------
__global__ void k_scan_c(const int* __restrict__ partial, const int* __restrict__ blocksums,
                         const int* __restrict__ deg, int* __restrict__ row_ptr,
                         int* __restrict__ cursor, float* __restrict__ inv_deg, int n, int E) {
  int i = blockIdx.x * blockDim.x + threadIdx.x;
  if (i >= n) return;
  int v = partial[i] + blocksums[i >> 10];
  row_ptr[i] = v;
  cursor[i] = v;
  int d = deg[i];
  inv_deg[i] = 1.0f / (float)(d > 1 ? d : 1);
  if (i == 0) row_ptr[n] = E;
}

// ---------- scatter edges into CSR ----------
__global__ void k_scatter(const int* __restrict__ src, const int* __restrict__ dst,
                          int* cursor, int* __restrict__ csr_src, int E) {
  int i = blockIdx.x * blockDim.x + threadIdx.x;
  int stride = gridDim.x * blockDim.x;
  for (; i < E; i += stride) {
    int p = atomicAdd(&cursor[dst[i]], 1);
    csr_src[p] = src[i];
  }
}

// ---------- mean aggregation: one wave per node, lane handles 2 cols (bf16x2) ----------
__global__ void k_aggregate(const ushort* __restrict__ hb, const int* __restrict__ row_ptr,
                            const int* __restrict__ csr_src, const float* __restrict__ inv_deg,
                            ushort* __restrict__ mb, int N) {
  int wave = blockIdx.x * (blockDim.x >> 6) + (threadIdx.x >> 6);
  int lane = threadIdx.x & 63;
  if (wave >= N) return;
  int rs = row_ptr[wave], re = row_ptr[wave + 1];
  float ax = 0.f, ay = 0.f;
  for (int base = rs; base < re; base += 64) {
    int nidx = 0;
    if (base + lane < re) nidx = csr_src[base + lane];
    int cnt = min(64, re - base);
    for (int i = 0; i < cnt; ++i) {
      int s = __shfl(nidx, i);
      uint w = reinterpret_cast<const uint*>(hb)[(size_t)s * 64 + lane];
      ax += bf2f(w & 0xffffu);
      ay += bf2f(w >> 16);
    }
  }
  float sc = inv_deg[wave];
  ax *= sc; ay *= sc;
  uint o = (uint)f2bf(ax) | ((uint)f2bf(ay) << 16);
  reinterpret_cast<uint*>(mb)[(size_t)wave * 64 + lane] = o;
}

// ---------- fused GEMM (K=256: [mean|h]) + bias + LayerNorm + ReLU ----------
// Block: 256 threads (4 waves), 128 rows per block, 32 rows per wave (2 MFMA row-tiles).
// B (weights) pre-swizzled in LDS; A loaded directly from global (16B/lane, frag layout).
__global__ __launch_bounds__(256) void k_gemm_ln(
    const ushort* __restrict__ Amean, const ushort* __restrict__ Ah,
    const ushort* __restrict__ Wsw_l, const float* __restrict__ bl,
    const float* __restrict__ g, const float* __restrict__ be,
    ushort* __restrict__ out_b, float* __restrict__ out_f, int N) {
  __shared__ ushort lW[32768];  // 64 KB: [(kb*8+jt)][lane][8]
  int t = threadIdx.x;
  {
    const uint4* srcp = reinterpret_cast<const uint4*>(Wsw_l);
    uint4* dstp = reinterpret_cast<uint4*>(lW);
#pragma unroll
    for (int i = 0; i < 16; ++i) dstp[t + 256 * i] = srcp[t + 256 * i];
  }
  __syncthreads();
  int wave = t >> 6, lane = t & 63;
  int m = lane & 15;               // col within 16-col tile; also A row within tile
  int koff = (lane >> 4) * 8;      // k sub-offset within 32-k block
  size_t row0 = (size_t)(blockIdx.x * 128 + wave * 32 + m);

  floatx4 acc[2][8];
#pragma unroll
  for (int ti = 0; ti < 2; ++ti)
#pragma unroll
    for (int jt = 0; jt < 8; ++jt) acc[ti][jt] = (floatx4){0.f, 0.f, 0.f, 0.f};

#pragma unroll
  for (int kb = 0; kb < 8; ++kb) {
    const ushort* Asrc = (kb < 4) ? Amean : Ah;
    int ke = (kb & 3) * 32 + koff;  // element offset within a 128-wide row
    bf16x8 a0 = *reinterpret_cast<const bf16x8*>(Asrc + row0 * 128 + ke);
    bf16x8 a1 = *reinterpret_cast<const bf16x8*>(Asrc + (row0 + 16) * 128 + ke);
#pragma unroll
    for (int jt = 0; jt < 8; ++jt) {
      bf16x8 b = *reinterpret_cast<const bf16x8*>(lW + ((kb * 8 + jt) * 64 + lane) * 8);
      acc[0][jt] = __builtin_amdgcn_mfma_f32_16x16x32_bf16(a0, b, acc[0][jt], 0, 0, 0);
      acc[1][jt] = __builtin_amdgcn_mfma_f32_16x16x32_bf16(a1, b, acc[1][jt], 0, 0, 0);
    }
  }

  // epilogue: bias + LayerNorm (per row, 128 cols) + ReLU + store
  float blv[8], gv[8], bev[8];
#pragma unroll
  for (int jt = 0; jt < 8; ++jt) {
    int c = jt * 16 + m;
    blv[jt] = bl[c]; gv[jt] = g[c]; bev[jt] = be[c];
  }
#pragma unroll
  for (int ti = 0; ti < 2; ++ti) {
    float s[4] = {0, 0, 0, 0}, q[4] = {0, 0, 0, 0};
#pragma unroll
    for (int jt = 0; jt < 8; ++jt) {
#pragma unroll
      for (int r = 0; r < 4; ++r) {
        float v = acc[ti][jt][r] + blv[jt];
        acc[ti][jt][r] = v;
        s[r] += v; q[r] += v * v;
      }
    }
#pragma unroll
    for (int off = 1; off < 16; off <<= 1) {
#pragma unroll
      for (int r = 0; r < 4; ++r) {
        s[r] += __shfl_xor(s[r], off);
        q[r] += __shfl_xor(q[r], off);
      }
    }
    int rowbase = blockIdx.x * 128 + wave * 32 + ti * 16 + (lane >> 4) * 4;
#pragma unroll
    for (int r = 0; r < 4; ++r) {
      int row = rowbase + r;
      if (row < N) {
        float mu = s[r] * 0.0078125f;
        float var = q[r] * 0.0078125f - mu * mu;
        float rstd = rsqrtf(var + 1e-5f);
#pragma unroll
        for (int jt = 0; jt < 8; ++jt) {
          float y = (acc[ti][jt][r] - mu) * rstd * gv[jt] + bev[jt];
          y = fmaxf(y, 0.f);
          int c = jt * 16 + m;
          if (out_f) out_f[(size_t)row * 128 + c] = y;
          else out_b[(size_t)row * 128 + c] = f2bf(y);
        }
      }
    }
  }
}

extern "C" void kernel_launch(void* const* d_in, const int* in_sizes, int n_in,
                              void* d_out, int out_size, void* d_ws, size_t ws_size,
                              hipStream_t stream) {
  const float* x   = (const float*)d_in[0];
  const int*   ei  = (const int*)d_in[1];
  const float* Wl0 = (const float*)d_in[2];
  const float* bl0 = (const float*)d_in[3];
  const float* Wr0 = (const float*)d_in[4];
  const float* g0  = (const float*)d_in[5];
  const float* be0 = (const float*)d_in[6];
  const float* Wl  = (const float*)d_in[7];
  const float* bls = (const float*)d_in[8];
  const float* Wr  = (const float*)d_in[9];
  const float* gs  = (const float*)d_in[10];
  const float* bes = (const float*)d_in[11];

  int N = in_sizes[0] / 128;
  int E = in_sizes[1] / 2;
  int Np = (N + 127) & ~127;
  const int* srcv = ei;
  const int* dstv = ei + E;

  char* p = (char*)d_ws;
  auto alloc = [&](size_t bytes) {
    char* r = p;
    p += (bytes + 255) & ~(size_t)255;
    return r;
  };
  ushort* xb  = (ushort*)alloc((size_t)Np * 128 * 2);
  ushort* hb  = (ushort*)alloc((size_t)Np * 128 * 2);
  ushort* mb  = (ushort*)alloc((size_t)Np * 128 * 2);
  ushort* Wsw = (ushort*)alloc((size_t)3 * 64 * 64 * 8 * 2);
  int*   deg       = (int*)alloc((size_t)N * 4);
  int*   row_ptr   = (int*)alloc((size_t)(N + 1) * 4);
  int*   cursor    = (int*)alloc((size_t)N * 4);
  int*   partial   = (int*)alloc((size_t)N * 4);
  int*   blocksums = (int*)alloc(4096);
  float* inv_deg   = (float*)alloc((size_t)N * 4);
  int*   csr_src   = (int*)alloc((size_t)E * 4);

  hipMemsetAsync(deg, 0, (size_t)N * 4, stream);

  { int n4 = N * 32; k_cast_bf16<<<(n4 + 255) / 256, 256, 0, stream>>>(x, xb, n4); }
  k_swizzle_w<<<48, 256, 0, stream>>>(Wl0, Wr0, Wl, Wr, Wsw);
  k_deg<<<1024, 256, 0, stream>>>(dstv, deg, E);
  int nScanBlocks = (N + 1023) / 1024;
  k_scan_a<<<nScanBlocks, 256, 0, stream>>>(deg, partial, blocksums, N);
  k_scan_b<<<1, 64, 0, stream>>>(blocksums, nScanBlocks);
  k_scan_c<<<(N + 255) / 256, 256, 0, stream>>>(partial, blocksums, deg, row_ptr, cursor,
                                                inv_deg, N, E);
  k_scatter<<<1024, 256, 0, stream>>>(srcv, dstv, cursor, csr_src, E);

  dim3 aggGrid((N + 3) / 4), gemmGrid(Np / 128);
  // layer 0
  k_aggregate<<<aggGrid, 256, 0, stream>>>(xb, row_ptr, csr_src, inv_deg, mb, N);
  k_gemm_ln<<<gemmGrid, 256, 0, stream>>>(mb, xb, Wsw + 0 * 32768, bl0, g0, be0,
                                          hb, nullptr, N);
  // layer 1
  k_aggregate<<<aggGrid, 256, 0, stream>>>(hb, row_ptr, csr_src, inv_deg, mb, N);
  k_gemm_ln<<<gemmGrid, 256, 0, stream>>>(mb, hb, Wsw + 1 * 32768, bls + 0, gs + 0, bes + 0,
                                          xb, nullptr, N);
  // layer 2 (writes f32 directly to d_out)
  k_aggregate<<<aggGrid, 256, 0, stream>>>(xb, row_ptr, csr_src, inv_deg, mb, N);
  k_gemm_ln<<<gemmGrid, 256, 0, stream>>>(mb, xb, Wsw + 2 * 32768, bls + 128, gs + 128,
                                          bes + 128, nullptr, (float*)d_out, N);
}

// Round 2
// 484.394 us; speedup vs baseline: 1.5289x; 1.5289x over previous
//
#include <hip/hip_runtime.h>
#include <stdint.h>

typedef unsigned int uint;
typedef unsigned short ushort;

typedef float floatx4 __attribute__((ext_vector_type(4)));
typedef __bf16 bf16x8 __attribute__((ext_vector_type(8)));

#define NPB 512          // nodes per bucket (dst >> 9)
#define PART_BLOCKS 256  // blocks in hist/partition passes

// ---------- bf16 helpers (RNE, bit-level) ----------
__device__ __forceinline__ ushort f2bf(float f) {
  uint u = __float_as_uint(f);
  u += 0x7fffu + ((u >> 16) & 1u);
  return (ushort)(u >> 16);
}
__device__ __forceinline__ float bf2f(uint bits) {
  return __uint_as_float(bits << 16);
}
__device__ __forceinline__ uint pack2(float a, float b) {
  return (uint)f2bf(a) | ((uint)f2bf(b) << 16);
}

// ---------- cast x (f32) -> bf16 ----------
__global__ void k_cast_bf16(const float* __restrict__ in, ushort* __restrict__ out, int n4) {
  int i = blockIdx.x * blockDim.x + threadIdx.x;
  if (i >= n4) return;
  float4 v = reinterpret_cast<const float4*>(in)[i];
  ushort4 o;
  o.x = f2bf(v.x); o.y = f2bf(v.y); o.z = f2bf(v.z); o.w = f2bf(v.w);
  reinterpret_cast<ushort4*>(out)[i] = o;
}

// ---------- swizzle all 3 layers' [Wl;Wr] into MFMA B-fragment order ----------
__global__ void k_swizzle_w(const float* __restrict__ Wl0, const float* __restrict__ Wr0,
                            const float* __restrict__ Wl, const float* __restrict__ Wr,
                            ushort* __restrict__ Wsw) {
  int t = blockIdx.x * blockDim.x + threadIdx.x;
  if (t >= 3 * 64 * 64) return;
  int lane = t & 63;
  int blk = (t >> 6) & 63;
  int l = t >> 12;
  int kb = blk >> 3, jt = blk & 7;
  int col = jt * 16 + (lane & 15);
  ushort tmp[8];
#pragma unroll
  for (int j = 0; j < 8; ++j) {
    int k = kb * 32 + (lane >> 4) * 8 + j;
    float v;
    if (k < 128) {
      v = (l == 0) ? Wl0[k * 128 + col] : Wl[(l - 1) * 16384 + k * 128 + col];
    } else {
      int k2 = k - 128;
      v = (l == 0) ? Wr0[k2 * 128 + col] : Wr[(l - 1) * 16384 + k2 * 128 + col];
    }
    tmp[j] = f2bf(v);
  }
  reinterpret_cast<uint4*>(Wsw)[t] = *reinterpret_cast<uint4*>(tmp);
}

// ---------- bucket histogram: cnt[bucket * PART_BLOCKS + block] ----------
__global__ __launch_bounds__(256) void k_hist(const int* __restrict__ dst,
                                              int* __restrict__ cnt, int E, int nbuck) {
  __shared__ int lc[256];
  int t = threadIdx.x;
  lc[t] = 0;
  __syncthreads();
  int per = (E + PART_BLOCKS - 1) / PART_BLOCKS;
  int s = blockIdx.x * per, e = min(E, s + per);
  for (int i = s + t; i < e; i += 256) atomicAdd(&lc[dst[i] >> 9], 1);
  __syncthreads();
  if (t < nbuck) cnt[t * PART_BLOCKS + blockIdx.x] = lc[t];
}

// ---------- generic scan pass A: 1024-chunk exclusive scan + block sums ----------
__global__ void k_scan_a(const int* __restrict__ in, int* __restrict__ partial,
                         int* __restrict__ blocksums, int n) {
  __shared__ int sm[256];
  int t = threadIdx.x;
  int base = blockIdx.x * 1024 + t * 4;
  int v0 = 0, v1 = 0, v2 = 0, v3 = 0;
  if (base + 0 < n) v0 = in[base + 0];
  if (base + 1 < n) v1 = in[base + 1];
  if (base + 2 < n) v2 = in[base + 2];
  if (base + 3 < n) v3 = in[base + 3];
  int mysum = v0 + v1 + v2 + v3;
  sm[t] = mysum;
  __syncthreads();
  for (int off = 1; off < 256; off <<= 1) {
    int x = (t >= off) ? sm[t - off] : 0;
    __syncthreads();
    sm[t] += x;
    __syncthreads();
  }
  int excl = sm[t] - mysum;
  if (t == 255) blocksums[blockIdx.x] = sm[255];
  if (base + 0 < n) partial[base + 0] = excl;
  if (base + 1 < n) partial[base + 1] = excl + v0;
  if (base + 2 < n) partial[base + 2] = excl + v0 + v1;
  if (base + 3 < n) partial[base + 3] = excl + v0 + v1 + v2;
}

__global__ void k_scan_b(int* blocksums, int nb) {
  if (threadIdx.x == 0 && blockIdx.x == 0) {
    int run = 0;
    for (int i = 0; i < nb; ++i) { int v = blocksums[i]; blocksums[i] = run; run += v; }
  }
}

__global__ void k_scan_apply(const int* __restrict__ partial, const int* __restrict__ blocksums,
                             int* __restrict__ out, int n) {
  int i = blockIdx.x * blockDim.x + threadIdx.x;
  if (i >= n) return;
  out[i] = partial[i] + blocksums[i >> 10];
}

// ---------- partition edges into bucket-major packed array ----------
// part[pos] = (src << 9) | (dst & 511)
__global__ __launch_bounds__(256) void k_partition(const int* __restrict__ src,
                                                   const int* __restrict__ dst,
                                                   const int* __restrict__ offsets,
                                                   uint* __restrict__ part, int E, int nbuck) {
  __shared__ int cur[256];
  int t = threadIdx.x;
  if (t < nbuck) cur[t] = offsets[t * PART_BLOCKS + blockIdx.x];
  __syncthreads();
  int per = (E + PART_BLOCKS - 1) / PART_BLOCKS;
  int s = blockIdx.x * per, e = min(E, s + per);
  for (int i = s + t; i < e; i += 256) {
    int d = dst[i];
    int k = d >> 9;
    int pos = atomicAdd(&cur[k], 1);
    part[pos] = ((uint)src[i] << 9) | (uint)(d & 511);
  }
}

// ---------- per-bucket LDS counting sort -> csr_src, row_ptr, inv_deg ----------
__global__ __launch_bounds__(256) void k_build(const uint* __restrict__ part,
                                               const int* __restrict__ offsets,
                                               int* __restrict__ row_ptr,
                                               float* __restrict__ inv_deg,
                                               int* __restrict__ csr_src,
                                               int E, int N, int nbuck) {
  int k = blockIdx.x;
  __shared__ int cnt[512];
  __shared__ int sm[256];
  __shared__ int range[2];
  int t = threadIdx.x;
  if (t == 0) {
    range[0] = offsets[k * PART_BLOCKS];
    range[1] = (k + 1 < nbuck) ? offsets[(k + 1) * PART_BLOCKS] : E;
  }
  cnt[t] = 0; cnt[t + 256] = 0;
  __syncthreads();
  int base = range[0], end = range[1];
  for (int i = base + t; i < end; i += 256) atomicAdd(&cnt[part[i] & 511u], 1);
  __syncthreads();
  int a = cnt[2 * t], b = cnt[2 * t + 1];
  int psum = a + b;
  sm[t] = psum;
  __syncthreads();
  for (int off = 1; off < 256; off <<= 1) {
    int x = (t >= off) ? sm[t - off] : 0;
    __syncthreads();
    sm[t] += x;
    __syncthreads();
  }
  int excl = sm[t] - psum;
  cnt[2 * t] = excl;
  cnt[2 * t + 1] = excl + a;
  int node0 = (k << 9) + 2 * t;
  if (node0 < N) { row_ptr[node0] = base + excl;     inv_deg[node0] = 1.0f / (float)(a > 1 ? a : 1); }
  if (node0 + 1 < N) { row_ptr[node0 + 1] = base + excl + a; inv_deg[node0 + 1] = 1.0f / (float)(b > 1 ? b : 1); }
  if (k == nbuck - 1 && t == 0) row_ptr[N] = E;
  __syncthreads();
  for (int i = base + t; i < end; i += 256) {
    uint p = part[i];
    int pos = atomicAdd(&cnt[p & 511u], 1);
    csr_src[base + pos] = (int)(p >> 9);
  }
}

// ---------- mean aggregation: 16-lane groups, uint4 (16B) per lane ----------
// One wave handles 4 nodes; one VMEM instruction gathers 4 full 256B rows.
__global__ __launch_bounds__(256) void k_aggregate(
    const ushort* __restrict__ hb, const int* __restrict__ row_ptr,
    const int* __restrict__ csr_src, const float* __restrict__ inv_deg,
    ushort* __restrict__ mb, int N) {
  const uint4* __restrict__ hb4 = reinterpret_cast<const uint4*>(hb);
  int wave = threadIdx.x >> 6, lane = threadIdx.x & 63;
  int g = lane >> 4, l16 = lane & 15;
  int node = blockIdx.x * 16 + wave * 4 + g;
  int rs = 0, re = 0;
  if (node < N) { rs = row_ptr[node]; re = row_ptr[node + 1]; }
  float ax[8];
#pragma unroll
  for (int j = 0; j < 8; ++j) ax[j] = 0.f;

  for (int base = rs; ; base += 16) {
    int myoff = base + l16;
    int nidx = (myoff < re) ? csr_src[myoff] : -1;
    if (__ballot(nidx >= 0) == 0ull) break;
#pragma unroll
    for (int i = 0; i < 16; ++i) {
      int s = __shfl(nidx, (g << 4) + i);
      if (s >= 0) {
        uint4 w = hb4[(size_t)s * 16 + l16];
        ax[0] += bf2f(w.x & 0xffffu); ax[1] += bf2f(w.x >> 16);
        ax[2] += bf2f(w.y & 0xffffu); ax[3] += bf2f(w.y >> 16);
        ax[4] += bf2f(w.z & 0xffffu); ax[5] += bf2f(w.z >> 16);
        ax[6] += bf2f(w.w & 0xffffu); ax[7] += bf2f(w.w >> 16);
      }
    }
  }
  if (node < N) {
    float sc = inv_deg[node];
    uint4 o;
    o.x = pack2(ax[0] * sc, ax[1] * sc);
    o.y = pack2(ax[2] * sc, ax[3] * sc);
    o.z = pack2(ax[4] * sc, ax[5] * sc);
    o.w = pack2(ax[6] * sc, ax[7] * sc);
    reinterpret_cast<uint4*>(mb)[(size_t)node * 16 + l16] = o;
  }
}

// ---------- fused GEMM (K=256: [mean|h]) + bias + LayerNorm + ReLU ----------
__global__ __launch_bounds__(256) void k_gemm_ln(
    const ushort* __restrict__ Amean, const ushort* __restrict__ Ah,
    const ushort* __restrict__ Wsw_l, const float* __restrict__ bl,
    const float* __restrict__ g, const float* __restrict__ be,
    ushort* __restrict__ out_b, float* __restrict__ out_f, int N) {
  __shared__ ushort lW[32768];
  int t = threadIdx.x;
  {
    const uint4* srcp = reinterpret_cast<const uint4*>(Wsw_l);
    uint4* dstp = reinterpret_cast<uint4*>(lW);
#pragma unroll
    for (int i = 0; i < 16; ++i) dstp[t + 256 * i] = srcp[t + 256 * i];
  }
  __syncthreads();
  int wave = t >> 6, lane = t & 63;
  int m = lane & 15;
  int koff = (lane >> 4) * 8;
  size_t row0 = (size_t)(blockIdx.x * 128 + wave * 32 + m);

  floatx4 acc[2][8];
#pragma unroll
  for (int ti = 0; ti < 2; ++ti)
#pragma unroll
    for (int jt = 0; jt < 8; ++jt) acc[ti][jt] = (floatx4){0.f, 0.f, 0.f, 0.f};

#pragma unroll
  for (int kb = 0; kb < 8; ++kb) {
    const ushort* Asrc = (kb < 4) ? Amean : Ah;
    int ke = (kb & 3) * 32 + koff;
    bf16x8 a0 = *reinterpret_cast<const bf16x8*>(Asrc + row0 * 128 + ke);
    bf16x8 a1 = *reinterpret_cast<const bf16x8*>(Asrc + (row0 + 16) * 128 + ke);
#pragma unroll
    for (int jt = 0; jt < 8; ++jt) {
      bf16x8 b = *reinterpret_cast<const bf16x8*>(lW + ((kb * 8 + jt) * 64 + lane) * 8);
      acc[0][jt] = __builtin_amdgcn_mfma_f32_16x16x32_bf16(a0, b, acc[0][jt], 0, 0, 0);
      acc[1][jt] = __builtin_amdgcn_mfma_f32_16x16x32_bf16(a1, b, acc[1][jt], 0, 0, 0);
    }
  }

  float blv[8], gv[8], bev[8];
#pragma unroll
  for (int jt = 0; jt < 8; ++jt) {
    int c = jt * 16 + m;
    blv[jt] = bl[c]; gv[jt] = g[c]; bev[jt] = be[c];
  }
#pragma unroll
  for (int ti = 0; ti < 2; ++ti) {
    float s[4] = {0, 0, 0, 0}, q[4] = {0, 0, 0, 0};
#pragma unroll
    for (int jt = 0; jt < 8; ++jt) {
#pragma unroll
      for (int r = 0; r < 4; ++r) {
        float v = acc[ti][jt][r] + blv[jt];
        acc[ti][jt][r] = v;
        s[r] += v; q[r] += v * v;
      }
    }
#pragma unroll
    for (int off = 1; off < 16; off <<= 1) {
#pragma unroll
      for (int r = 0; r < 4; ++r) {
        s[r] += __shfl_xor(s[r], off);
        q[r] += __shfl_xor(q[r], off);
      }
    }
    int rowbase = blockIdx.x * 128 + wave * 32 + ti * 16 + (lane >> 4) * 4;
#pragma unroll
    for (int r = 0; r < 4; ++r) {
      int row = rowbase + r;
      if (row < N) {
        float mu = s[r] * 0.0078125f;
        float var = q[r] * 0.0078125f - mu * mu;
        float rstd = rsqrtf(var + 1e-5f);
#pragma unroll
        for (int jt = 0; jt < 8; ++jt) {
          float y = (acc[ti][jt][r] - mu) * rstd * gv[jt] + bev[jt];
          y = fmaxf(y, 0.f);
          int c = jt * 16 + m;
          if (out_f) out_f[(size_t)row * 128 + c] = y;
          else out_b[(size_t)row * 128 + c] = f2bf(y);
        }
      }
    }
  }
}

extern "C" void kernel_launch(void* const* d_in, const int* in_sizes, int n_in,
                              void* d_out, int out_size, void* d_ws, size_t ws_size,
                              hipStream_t stream) {
  const float* x   = (const float*)d_in[0];
  const int*   ei  = (const int*)d_in[1];
  const float* Wl0 = (const float*)d_in[2];
  const float* bl0 = (const float*)d_in[3];
  const float* Wr0 = (const float*)d_in[4];
  const float* g0  = (const float*)d_in[5];
  const float* be0 = (const float*)d_in[6];
  const float* Wl  = (const float*)d_in[7];
  const float* bls = (const float*)d_in[8];
  const float* Wr  = (const float*)d_in[9];
  const float* gs  = (const float*)d_in[10];
  const float* bes = (const float*)d_in[11];

  int N = in_sizes[0] / 128;
  int E = in_sizes[1] / 2;
  int Np = (N + 127) & ~127;
  int nbuck = (N + NPB - 1) / NPB;
  const int* srcv = ei;
  const int* dstv = ei + E;

  char* p = (char*)d_ws;
  auto alloc = [&](size_t bytes) {
    char* r = p;
    p += (bytes + 255) & ~(size_t)255;
    return r;
  };
  ushort* xb  = (ushort*)alloc((size_t)Np * 128 * 2);
  ushort* hb  = (ushort*)alloc((size_t)Np * 128 * 2);
  ushort* mb  = (ushort*)alloc((size_t)Np * 128 * 2);
  ushort* Wsw = (ushort*)alloc((size_t)3 * 64 * 64 * 8 * 2);
  int*   cntm      = (int*)alloc((size_t)nbuck * PART_BLOCKS * 4);
  int*   offsets   = (int*)alloc((size_t)nbuck * PART_BLOCKS * 4);
  int*   blocksums = (int*)alloc(8192);
  int*   row_ptr   = (int*)alloc((size_t)(N + 1) * 4);
  float* inv_deg   = (float*)alloc((size_t)N * 4);
  uint*  part      = (uint*)alloc((size_t)E * 4);
  int*   csr_src   = (int*)alloc((size_t)E * 4);

  // CSR build (atomic-free in global memory, all LDS atomics)
  int nscan = nbuck * PART_BLOCKS;
  int nScanBlocks = (nscan + 1023) / 1024;
  k_hist<<<PART_BLOCKS, 256, 0, stream>>>(dstv, cntm, E, nbuck);
  k_scan_a<<<nScanBlocks, 256, 0, stream>>>(cntm, cntm, blocksums, nscan);
  k_scan_b<<<1, 64, 0, stream>>>(blocksums, nScanBlocks);
  k_scan_apply<<<(nscan + 255) / 256, 256, 0, stream>>>(cntm, blocksums, offsets, nscan);
  k_partition<<<PART_BLOCKS, 256, 0, stream>>>(srcv, dstv, offsets, part, E, nbuck);
  k_build<<<nbuck, 256, 0, stream>>>(part, offsets, row_ptr, inv_deg, csr_src, E, N, nbuck);

  { int n4 = N * 32; k_cast_bf16<<<(n4 + 255) / 256, 256, 0, stream>>>(x, xb, n4); }
  k_swizzle_w<<<48, 256, 0, stream>>>(Wl0, Wr0, Wl, Wr, Wsw);

  dim3 aggGrid((N + 15) / 16), gemmGrid(Np / 128);
  // layer 0
  k_aggregate<<<aggGrid, 256, 0, stream>>>(xb, row_ptr, csr_src, inv_deg, mb, N);
  k_gemm_ln<<<gemmGrid, 256, 0, stream>>>(mb, xb, Wsw + 0 * 32768, bl0, g0, be0,
                                          hb, nullptr, N);
  // layer 1
  k_aggregate<<<aggGrid, 256, 0, stream>>>(hb, row_ptr, csr_src, inv_deg, mb, N);
  k_gemm_ln<<<gemmGrid, 256, 0, stream>>>(mb, hb, Wsw + 1 * 32768, bls + 0, gs + 0, bes + 0,
                                          xb, nullptr, N);
  // layer 2 (writes f32 directly to d_out)
  k_aggregate<<<aggGrid, 256, 0, stream>>>(xb, row_ptr, csr_src, inv_deg, mb, N);
  k_gemm_ln<<<gemmGrid, 256, 0, stream>>>(mb, xb, Wsw + 2 * 32768, bls + 128, gs + 128,
                                          bes + 128, nullptr, (float*)d_out, N);
}

// Round 3
// 470.311 us; speedup vs baseline: 1.5747x; 1.0299x over previous
//
#include <hip/hip_runtime.h>
#include <stdint.h>

typedef unsigned int uint;
typedef unsigned short ushort;

typedef float floatx4 __attribute__((ext_vector_type(4)));
typedef __bf16 bf16x8 __attribute__((ext_vector_type(8)));

#define NPB 512          // nodes per bucket (dst >> 9)
#define PART_BLOCKS 256  // blocks in hist/partition passes

// ---------- bf16 helpers (RNE, bit-level) ----------
__device__ __forceinline__ ushort f2bf(float f) {
  uint u = __float_as_uint(f);
  u += 0x7fffu + ((u >> 16) & 1u);
  return (ushort)(u >> 16);
}
__device__ __forceinline__ float bf2f(uint bits) {
  return __uint_as_float(bits << 16);
}
__device__ __forceinline__ uint pack2(float a, float b) {
  return (uint)f2bf(a) | ((uint)f2bf(b) << 16);
}

// ---------- cast x (f32) -> bf16 ----------
__global__ void k_cast_bf16(const float* __restrict__ in, ushort* __restrict__ out, int n4) {
  int i = blockIdx.x * blockDim.x + threadIdx.x;
  if (i >= n4) return;
  float4 v = reinterpret_cast<const float4*>(in)[i];
  ushort4 o;
  o.x = f2bf(v.x); o.y = f2bf(v.y); o.z = f2bf(v.z); o.w = f2bf(v.w);
  reinterpret_cast<ushort4*>(out)[i] = o;
}

// ---------- swizzle all 3 layers' [Wl;Wr] into MFMA B-fragment order ----------
__global__ void k_swizzle_w(const float* __restrict__ Wl0, const float* __restrict__ Wr0,
                            const float* __restrict__ Wl, const float* __restrict__ Wr,
                            ushort* __restrict__ Wsw) {
  int t = blockIdx.x * blockDim.x + threadIdx.x;
  if (t >= 3 * 64 * 64) return;
  int lane = t & 63;
  int blk = (t >> 6) & 63;
  int l = t >> 12;
  int kb = blk >> 3, jt = blk & 7;
  int col = jt * 16 + (lane & 15);
  ushort tmp[8];
#pragma unroll
  for (int j = 0; j < 8; ++j) {
    int k = kb * 32 + (lane >> 4) * 8 + j;
    float v;
    if (k < 128) {
      v = (l == 0) ? Wl0[k * 128 + col] : Wl[(l - 1) * 16384 + k * 128 + col];
    } else {
      int k2 = k - 128;
      v = (l == 0) ? Wr0[k2 * 128 + col] : Wr[(l - 1) * 16384 + k2 * 128 + col];
    }
    tmp[j] = f2bf(v);
  }
  reinterpret_cast<uint4*>(Wsw)[t] = *reinterpret_cast<uint4*>(tmp);
}

// ---------- bucket histogram: cnt[bucket * PART_BLOCKS + block] ----------
__global__ __launch_bounds__(256) void k_hist(const int* __restrict__ dst,
                                              int* __restrict__ cnt, int E, int nbuck) {
  __shared__ int lc[256];
  int t = threadIdx.x;
  lc[t] = 0;
  __syncthreads();
  int per = (E + PART_BLOCKS - 1) / PART_BLOCKS;
  int s = blockIdx.x * per, e = min(E, s + per);
  for (int i = s + t; i < e; i += 256) atomicAdd(&lc[dst[i] >> 9], 1);
  __syncthreads();
  if (t < nbuck) cnt[t * PART_BLOCKS + blockIdx.x] = lc[t];
}

// ---------- generic scan pass A ----------
__global__ void k_scan_a(const int* __restrict__ in, int* __restrict__ partial,
                         int* __restrict__ blocksums, int n) {
  __shared__ int sm[256];
  int t = threadIdx.x;
  int base = blockIdx.x * 1024 + t * 4;
  int v0 = 0, v1 = 0, v2 = 0, v3 = 0;
  if (base + 0 < n) v0 = in[base + 0];
  if (base + 1 < n) v1 = in[base + 1];
  if (base + 2 < n) v2 = in[base + 2];
  if (base + 3 < n) v3 = in[base + 3];
  int mysum = v0 + v1 + v2 + v3;
  sm[t] = mysum;
  __syncthreads();
  for (int off = 1; off < 256; off <<= 1) {
    int x = (t >= off) ? sm[t - off] : 0;
    __syncthreads();
    sm[t] += x;
    __syncthreads();
  }
  int excl = sm[t] - mysum;
  if (t == 255) blocksums[blockIdx.x] = sm[255];
  if (base + 0 < n) partial[base + 0] = excl;
  if (base + 1 < n) partial[base + 1] = excl + v0;
  if (base + 2 < n) partial[base + 2] = excl + v0 + v1;
  if (base + 3 < n) partial[base + 3] = excl + v0 + v1 + v2;
}

__global__ void k_scan_b(int* blocksums, int nb) {
  if (threadIdx.x == 0 && blockIdx.x == 0) {
    int run = 0;
    for (int i = 0; i < nb; ++i) { int v = blocksums[i]; blocksums[i] = run; run += v; }
  }
}

__global__ void k_scan_apply(const int* __restrict__ partial, const int* __restrict__ blocksums,
                             int* __restrict__ out, int n) {
  int i = blockIdx.x * blockDim.x + threadIdx.x;
  if (i >= n) return;
  out[i] = partial[i] + blocksums[i >> 10];
}

// ---------- partition edges into bucket-major packed array ----------
__global__ __launch_bounds__(256) void k_partition(const int* __restrict__ src,
                                                   const int* __restrict__ dst,
                                                   const int* __restrict__ offsets,
                                                   uint* __restrict__ part, int E, int nbuck) {
  __shared__ int cur[256];
  int t = threadIdx.x;
  if (t < nbuck) cur[t] = offsets[t * PART_BLOCKS + blockIdx.x];
  __syncthreads();
  int per = (E + PART_BLOCKS - 1) / PART_BLOCKS;
  int s = blockIdx.x * per, e = min(E, s + per);
  for (int i = s + t; i < e; i += 256) {
    int d = dst[i];
    int k = d >> 9;
    int pos = atomicAdd(&cur[k], 1);
    part[pos] = ((uint)src[i] << 9) | (uint)(d & 511);
  }
}

// ---------- per-bucket LDS counting sort -> PADDED csr (pad to x16 with sentinel N) ----
__global__ __launch_bounds__(256) void k_build(const uint* __restrict__ part,
                                               const int* __restrict__ offsets,
                                               int* __restrict__ row_start,
                                               int* __restrict__ nchunks,
                                               float* __restrict__ inv_deg,
                                               int* __restrict__ csr_pad,
                                               int E, int N, int nbuck) {
  int k = blockIdx.x;
  __shared__ int cnt[512];
  __shared__ int sm[256];
  __shared__ int rng[2];
  int t = threadIdx.x;
  if (t == 0) {
    rng[0] = offsets[k * PART_BLOCKS];
    rng[1] = (k + 1 < nbuck) ? offsets[(k + 1) * PART_BLOCKS] : E;
  }
  cnt[t] = 0; cnt[t + 256] = 0;
  __syncthreads();
  int base = rng[0], end = rng[1];
  int cbase = base + k * 8192;  // padded-array base (per-bucket slack = 8192 >= 15*512)
  for (int i = base + t; i < end; i += 256) atomicAdd(&cnt[part[i] & 511u], 1);
  __syncthreads();
  int a = cnt[2 * t], b = cnt[2 * t + 1];
  int pa = (a + 15) & ~15, pb = (b + 15) & ~15;
  int psum = pa + pb;
  sm[t] = psum;
  __syncthreads();
  for (int off = 1; off < 256; off <<= 1) {
    int x = (t >= off) ? sm[t - off] : 0;
    __syncthreads();
    sm[t] += x;
    __syncthreads();
  }
  int excl = sm[t] - psum;
  cnt[2 * t] = excl;
  cnt[2 * t + 1] = excl + pa;
  int node0 = (k << 9) + 2 * t;
  if (node0 < N) {
    row_start[node0] = cbase + excl;
    nchunks[node0] = pa >> 4;
    inv_deg[node0] = 1.0f / (float)(a > 1 ? a : 1);
  }
  if (node0 + 1 < N) {
    row_start[node0 + 1] = cbase + excl + pa;
    nchunks[node0 + 1] = pb >> 4;
    inv_deg[node0 + 1] = 1.0f / (float)(b > 1 ? b : 1);
  }
  __syncthreads();
  for (int i = base + t; i < end; i += 256) {
    uint p = part[i];
    int pos = atomicAdd(&cnt[p & 511u], 1);
    csr_pad[cbase + pos] = (int)(p >> 9);
  }
  // pad fill with sentinel N (zero row); disjoint from sort targets, no sync needed
  for (int i = a; i < pa; ++i) csr_pad[cbase + excl + i] = N;
  for (int i = b; i < pb; ++i) csr_pad[cbase + excl + pa + i] = N;
}

// ---------- mean aggregation: 16-lane groups, 16 gathers in flight ----------
// Branch-free inner loop over padded chunks of 16 neighbors; sentinel row N is zero.
__global__ __launch_bounds__(256, 4) void k_aggregate(
    const ushort* __restrict__ hb, const int* __restrict__ row_start,
    const int* __restrict__ nchunks, const float* __restrict__ inv_deg,
    const int* __restrict__ csr_pad, ushort* __restrict__ mb, int N) {
  const uint4* __restrict__ hb4 = reinterpret_cast<const uint4*>(hb);
  int wave = threadIdx.x >> 6, lane = threadIdx.x & 63;
  int g = lane >> 4, l16 = lane & 15;
  int node = blockIdx.x * 16 + wave * 4 + g;
  int rs = 0, nch = 0;
  if (node < N) { rs = row_start[node]; nch = nchunks[node]; }
  float ax[8];
#pragma unroll
  for (int j = 0; j < 8; ++j) ax[j] = 0.f;

  for (int c = 0; c < nch; ++c) {
    int nidx = csr_pad[rs + (c << 4) + l16];
    uint4 w[16];
#pragma unroll
    for (int i = 0; i < 16; ++i) {
      int s = __shfl(nidx, (g << 4) + i);
      w[i] = hb4[(size_t)s * 16 + l16];
    }
#pragma unroll
    for (int i = 0; i < 16; ++i) {
      ax[0] += bf2f(w[i].x & 0xffffu); ax[1] += bf2f(w[i].x >> 16);
      ax[2] += bf2f(w[i].y & 0xffffu); ax[3] += bf2f(w[i].y >> 16);
      ax[4] += bf2f(w[i].z & 0xffffu); ax[5] += bf2f(w[i].z >> 16);
      ax[6] += bf2f(w[i].w & 0xffffu); ax[7] += bf2f(w[i].w >> 16);
    }
  }
  if (node < N) {
    float sc = inv_deg[node];
    uint4 o;
    o.x = pack2(ax[0] * sc, ax[1] * sc);
    o.y = pack2(ax[2] * sc, ax[3] * sc);
    o.z = pack2(ax[4] * sc, ax[5] * sc);
    o.w = pack2(ax[6] * sc, ax[7] * sc);
    reinterpret_cast<uint4*>(mb)[(size_t)node * 16 + l16] = o;
  }
}

// ---------- fused GEMM (K=256: [mean|h]) + bias + LayerNorm + ReLU ----------
__global__ __launch_bounds__(256) void k_gemm_ln(
    const ushort* __restrict__ Amean, const ushort* __restrict__ Ah,
    const ushort* __restrict__ Wsw_l, const float* __restrict__ bl,
    const float* __restrict__ g, const float* __restrict__ be,
    ushort* __restrict__ out_b, float* __restrict__ out_f, int N) {
  __shared__ ushort lW[32768];
  int t = threadIdx.x;
  {
    const uint4* srcp = reinterpret_cast<const uint4*>(Wsw_l);
    uint4* dstp = reinterpret_cast<uint4*>(lW);
#pragma unroll
    for (int i = 0; i < 16; ++i) dstp[t + 256 * i] = srcp[t + 256 * i];
  }
  __syncthreads();
  int wave = t >> 6, lane = t & 63;
  int m = lane & 15;
  int koff = (lane >> 4) * 8;
  size_t row0 = (size_t)(blockIdx.x * 128 + wave * 32 + m);

  floatx4 acc[2][8];
#pragma unroll
  for (int ti = 0; ti < 2; ++ti)
#pragma unroll
    for (int jt = 0; jt < 8; ++jt) acc[ti][jt] = (floatx4){0.f, 0.f, 0.f, 0.f};

#pragma unroll
  for (int kb = 0; kb < 8; ++kb) {
    const ushort* Asrc = (kb < 4) ? Amean : Ah;
    int ke = (kb & 3) * 32 + koff;
    bf16x8 a0 = *reinterpret_cast<const bf16x8*>(Asrc + row0 * 128 + ke);
    bf16x8 a1 = *reinterpret_cast<const bf16x8*>(Asrc + (row0 + 16) * 128 + ke);
#pragma unroll
    for (int jt = 0; jt < 8; ++jt) {
      bf16x8 b = *reinterpret_cast<const bf16x8*>(lW + ((kb * 8 + jt) * 64 + lane) * 8);
      acc[0][jt] = __builtin_amdgcn_mfma_f32_16x16x32_bf16(a0, b, acc[0][jt], 0, 0, 0);
      acc[1][jt] = __builtin_amdgcn_mfma_f32_16x16x32_bf16(a1, b, acc[1][jt], 0, 0, 0);
    }
  }

  float blv[8], gv[8], bev[8];
#pragma unroll
  for (int jt = 0; jt < 8; ++jt) {
    int c = jt * 16 + m;
    blv[jt] = bl[c]; gv[jt] = g[c]; bev[jt] = be[c];
  }
#pragma unroll
  for (int ti = 0; ti < 2; ++ti) {
    float s[4] = {0, 0, 0, 0}, q[4] = {0, 0, 0, 0};
#pragma unroll
    for (int jt = 0; jt < 8; ++jt) {
#pragma unroll
      for (int r = 0; r < 4; ++r) {
        float v = acc[ti][jt][r] + blv[jt];
        acc[ti][jt][r] = v;
        s[r] += v; q[r] += v * v;
      }
    }
#pragma unroll
    for (int off = 1; off < 16; off <<= 1) {
#pragma unroll
      for (int r = 0; r < 4; ++r) {
        s[r] += __shfl_xor(s[r], off);
        q[r] += __shfl_xor(q[r], off);
      }
    }
    int rowbase = blockIdx.x * 128 + wave * 32 + ti * 16 + (lane >> 4) * 4;
#pragma unroll
    for (int r = 0; r < 4; ++r) {
      int row = rowbase + r;
      if (row < N) {
        float mu = s[r] * 0.0078125f;
        float var = q[r] * 0.0078125f - mu * mu;
        float rstd = rsqrtf(var + 1e-5f);
#pragma unroll
        for (int jt = 0; jt < 8; ++jt) {
          float y = (acc[ti][jt][r] - mu) * rstd * gv[jt] + bev[jt];
          y = fmaxf(y, 0.f);
          int c = jt * 16 + m;
          if (out_f) out_f[(size_t)row * 128 + c] = y;
          else out_b[(size_t)row * 128 + c] = f2bf(y);
        }
      }
    }
  }
}

extern "C" void kernel_launch(void* const* d_in, const int* in_sizes, int n_in,
                              void* d_out, int out_size, void* d_ws, size_t ws_size,
                              hipStream_t stream) {
  const float* x   = (const float*)d_in[0];
  const int*   ei  = (const int*)d_in[1];
  const float* Wl0 = (const float*)d_in[2];
  const float* bl0 = (const float*)d_in[3];
  const float* Wr0 = (const float*)d_in[4];
  const float* g0  = (const float*)d_in[5];
  const float* be0 = (const float*)d_in[6];
  const float* Wl  = (const float*)d_in[7];
  const float* bls = (const float*)d_in[8];
  const float* Wr  = (const float*)d_in[9];
  const float* gs  = (const float*)d_in[10];
  const float* bes = (const float*)d_in[11];

  int N = in_sizes[0] / 128;
  int E = in_sizes[1] / 2;
  int Np = (N + 127) & ~127;
  int nbuck = (N + NPB - 1) / NPB;
  const int* srcv = ei;
  const int* dstv = ei + E;

  char* p = (char*)d_ws;
  auto alloc = [&](size_t bytes) {
    char* r = p;
    p += (bytes + 255) & ~(size_t)255;
    return r;
  };
  ushort* xb  = (ushort*)alloc((size_t)Np * 128 * 2);
  ushort* hb  = (ushort*)alloc((size_t)Np * 128 * 2);
  ushort* mb  = (ushort*)alloc((size_t)Np * 128 * 2);
  ushort* Wsw = (ushort*)alloc((size_t)3 * 64 * 64 * 8 * 2);
  int*   cntm      = (int*)alloc((size_t)nbuck * PART_BLOCKS * 4);
  int*   offsets   = (int*)alloc((size_t)nbuck * PART_BLOCKS * 4);
  int*   blocksums = (int*)alloc(8192);
  int*   row_start = (int*)alloc((size_t)N * 4);
  int*   nchunks   = (int*)alloc((size_t)N * 4);
  float* inv_deg   = (float*)alloc((size_t)N * 4);
  uint*  part      = (uint*)alloc((size_t)E * 4);
  int*   csr_pad   = (int*)alloc(((size_t)E + (size_t)nbuck * 8192) * 4);

  // zero the sentinel row (index N) of both gather sources
  hipMemsetAsync(xb + (size_t)N * 128, 0, 256, stream);
  hipMemsetAsync(hb + (size_t)N * 128, 0, 256, stream);

  // CSR build (bucket radix, all atomics in LDS)
  int nscan = nbuck * PART_BLOCKS;
  int nScanBlocks = (nscan + 1023) / 1024;
  k_hist<<<PART_BLOCKS, 256, 0, stream>>>(dstv, cntm, E, nbuck);
  k_scan_a<<<nScanBlocks, 256, 0, stream>>>(cntm, cntm, blocksums, nscan);
  k_scan_b<<<1, 64, 0, stream>>>(blocksums, nScanBlocks);
  k_scan_apply<<<(nscan + 255) / 256, 256, 0, stream>>>(cntm, blocksums, offsets, nscan);
  k_partition<<<PART_BLOCKS, 256, 0, stream>>>(srcv, dstv, offsets, part, E, nbuck);
  k_build<<<nbuck, 256, 0, stream>>>(part, offsets, row_start, nchunks, inv_deg, csr_pad,
                                     E, N, nbuck);

  { int n4 = N * 32; k_cast_bf16<<<(n4 + 255) / 256, 256, 0, stream>>>(x, xb, n4); }
  k_swizzle_w<<<48, 256, 0, stream>>>(Wl0, Wr0, Wl, Wr, Wsw);

  dim3 aggGrid((N + 15) / 16), gemmGrid(Np / 128);
  // layer 0
  k_aggregate<<<aggGrid, 256, 0, stream>>>(xb, row_start, nchunks, inv_deg, csr_pad, mb, N);
  k_gemm_ln<<<gemmGrid, 256, 0, stream>>>(mb, xb, Wsw + 0 * 32768, bl0, g0, be0,
                                          hb, nullptr, N);
  // layer 1
  k_aggregate<<<aggGrid, 256, 0, stream>>>(hb, row_start, nchunks, inv_deg, csr_pad, mb, N);
  k_gemm_ln<<<gemmGrid, 256, 0, stream>>>(mb, hb, Wsw + 1 * 32768, bls + 0, gs + 0, bes + 0,
                                          xb, nullptr, N);
  // layer 2 (writes f32 directly to d_out)
  k_aggregate<<<aggGrid, 256, 0, stream>>>(xb, row_start, nchunks, inv_deg, csr_pad, mb, N);
  k_gemm_ln<<<gemmGrid, 256, 0, stream>>>(mb, xb, Wsw + 2 * 32768, bls + 128, gs + 128,
                                          bes + 128, nullptr, (float*)d_out, N);
}

// Round 4
// 466.819 us; speedup vs baseline: 1.5865x; 1.0075x over previous
//
#include <hip/hip_runtime.h>
#include <stdint.h>

typedef unsigned int uint;
typedef unsigned short ushort;

typedef float floatx4 __attribute__((ext_vector_type(4)));
typedef __bf16 bf16x8 __attribute__((ext_vector_type(8)));

#define NPB 512          // nodes per bucket (dst >> 9)
#define PART_BLOCKS 256  // blocks in hist/partition passes

// ---------- bf16 helpers (RNE, bit-level) ----------
__device__ __forceinline__ ushort f2bf(float f) {
  uint u = __float_as_uint(f);
  u += 0x7fffu + ((u >> 16) & 1u);
  return (ushort)(u >> 16);
}
__device__ __forceinline__ float bf2f(uint bits) {
  return __uint_as_float(bits << 16);
}
__device__ __forceinline__ uint pack2(float a, float b) {
  return (uint)f2bf(a) | ((uint)f2bf(b) << 16);
}

// ---------- cast x (f32) -> bf16 ----------
__global__ void k_cast_bf16(const float* __restrict__ in, ushort* __restrict__ out, int n4) {
  int i = blockIdx.x * blockDim.x + threadIdx.x;
  if (i >= n4) return;
  float4 v = reinterpret_cast<const float4*>(in)[i];
  ushort4 o;
  o.x = f2bf(v.x); o.y = f2bf(v.y); o.z = f2bf(v.z); o.w = f2bf(v.w);
  reinterpret_cast<ushort4*>(out)[i] = o;
}

// ---------- swizzle all 3 layers' [Wl;Wr] into MFMA B-fragment order ----------
__global__ void k_swizzle_w(const float* __restrict__ Wl0, const float* __restrict__ Wr0,
                            const float* __restrict__ Wl, const float* __restrict__ Wr,
                            ushort* __restrict__ Wsw) {
  int t = blockIdx.x * blockDim.x + threadIdx.x;
  if (t >= 3 * 64 * 64) return;
  int lane = t & 63;
  int blk = (t >> 6) & 63;
  int l = t >> 12;
  int kb = blk >> 3, jt = blk & 7;
  int col = jt * 16 + (lane & 15);
  ushort tmp[8];
#pragma unroll
  for (int j = 0; j < 8; ++j) {
    int k = kb * 32 + (lane >> 4) * 8 + j;
    float v;
    if (k < 128) {
      v = (l == 0) ? Wl0[k * 128 + col] : Wl[(l - 1) * 16384 + k * 128 + col];
    } else {
      int k2 = k - 128;
      v = (l == 0) ? Wr0[k2 * 128 + col] : Wr[(l - 1) * 16384 + k2 * 128 + col];
    }
    tmp[j] = f2bf(v);
  }
  reinterpret_cast<uint4*>(Wsw)[t] = *reinterpret_cast<uint4*>(tmp);
}

// ---------- bucket histogram: cnt[bucket * PART_BLOCKS + block] ----------
__global__ __launch_bounds__(256) void k_hist(const int* __restrict__ dst,
                                              int* __restrict__ cnt, int E, int nbuck) {
  __shared__ int lc[256];
  int t = threadIdx.x;
  lc[t] = 0;
  __syncthreads();
  int per = (E + PART_BLOCKS - 1) / PART_BLOCKS;
  int s = blockIdx.x * per, e = min(E, s + per);
  for (int i = s + t; i < e; i += 256) atomicAdd(&lc[dst[i] >> 9], 1);
  __syncthreads();
  if (t < nbuck) cnt[t * PART_BLOCKS + blockIdx.x] = lc[t];
}

// ---------- generic scan pass A ----------
__global__ void k_scan_a(const int* __restrict__ in, int* __restrict__ partial,
                         int* __restrict__ blocksums, int n) {
  __shared__ int sm[256];
  int t = threadIdx.x;
  int base = blockIdx.x * 1024 + t * 4;
  int v0 = 0, v1 = 0, v2 = 0, v3 = 0;
  if (base + 0 < n) v0 = in[base + 0];
  if (base + 1 < n) v1 = in[base + 1];
  if (base + 2 < n) v2 = in[base + 2];
  if (base + 3 < n) v3 = in[base + 3];
  int mysum = v0 + v1 + v2 + v3;
  sm[t] = mysum;
  __syncthreads();
  for (int off = 1; off < 256; off <<= 1) {
    int x = (t >= off) ? sm[t - off] : 0;
    __syncthreads();
    sm[t] += x;
    __syncthreads();
  }
  int excl = sm[t] - mysum;
  if (t == 255) blocksums[blockIdx.x] = sm[255];
  if (base + 0 < n) partial[base + 0] = excl;
  if (base + 1 < n) partial[base + 1] = excl + v0;
  if (base + 2 < n) partial[base + 2] = excl + v0 + v1;
  if (base + 3 < n) partial[base + 3] = excl + v0 + v1 + v2;
}

// ---------- parallel single-block scan of block sums (nb <= 256) ----------
__global__ void k_scan_b(int* blocksums, int nb) {
  __shared__ int sm[256];
  int t = threadIdx.x;
  int v = (t < nb) ? blocksums[t] : 0;
  sm[t] = v;
  __syncthreads();
  for (int off = 1; off < 256; off <<= 1) {
    int x = (t >= off) ? sm[t - off] : 0;
    __syncthreads();
    sm[t] += x;
    __syncthreads();
  }
  if (t < nb) blocksums[t] = sm[t] - v;  // exclusive
}

__global__ void k_scan_apply(const int* __restrict__ partial, const int* __restrict__ blocksums,
                             int* __restrict__ out, int n) {
  int i = blockIdx.x * blockDim.x + threadIdx.x;
  if (i >= n) return;
  out[i] = partial[i] + blocksums[i >> 10];
}

// ---------- partition edges into bucket-major packed array ----------
__global__ __launch_bounds__(256) void k_partition(const int* __restrict__ src,
                                                   const int* __restrict__ dst,
                                                   const int* __restrict__ offsets,
                                                   uint* __restrict__ part, int E, int nbuck) {
  __shared__ int cur[256];
  int t = threadIdx.x;
  if (t < nbuck) cur[t] = offsets[t * PART_BLOCKS + blockIdx.x];
  __syncthreads();
  int per = (E + PART_BLOCKS - 1) / PART_BLOCKS;
  int s = blockIdx.x * per, e = min(E, s + per);
  for (int i = s + t; i < e; i += 256) {
    int d = dst[i];
    int k = d >> 9;
    int pos = atomicAdd(&cur[k], 1);
    part[pos] = ((uint)src[i] << 9) | (uint)(d & 511);
  }
}

// ---------- per-bucket LDS counting sort -> PADDED csr (pad to x16 with sentinel N) ----
__global__ __launch_bounds__(256) void k_build(const uint* __restrict__ part,
                                               const int* __restrict__ offsets,
                                               int* __restrict__ row_start,
                                               int* __restrict__ nchunks,
                                               float* __restrict__ inv_deg,
                                               int* __restrict__ csr_pad,
                                               int E, int N, int nbuck) {
  int k = blockIdx.x;
  __shared__ int cnt[512];
  __shared__ int sm[256];
  __shared__ int rng[2];
  int t = threadIdx.x;
  if (t == 0) {
    rng[0] = offsets[k * PART_BLOCKS];
    rng[1] = (k + 1 < nbuck) ? offsets[(k + 1) * PART_BLOCKS] : E;
  }
  cnt[t] = 0; cnt[t + 256] = 0;
  __syncthreads();
  int base = rng[0], end = rng[1];
  int cbase = base + k * 8192;  // padded-array base (per-bucket slack = 8192 >= 15*512)
  for (int i = base + t; i < end; i += 256) atomicAdd(&cnt[part[i] & 511u], 1);
  __syncthreads();
  int a = cnt[2 * t], b = cnt[2 * t + 1];
  int pa = (a + 15) & ~15, pb = (b + 15) & ~15;
  int psum = pa + pb;
  sm[t] = psum;
  __syncthreads();
  for (int off = 1; off < 256; off <<= 1) {
    int x = (t >= off) ? sm[t - off] : 0;
    __syncthreads();
    sm[t] += x;
    __syncthreads();
  }
  int excl = sm[t] - psum;
  cnt[2 * t] = excl;
  cnt[2 * t + 1] = excl + pa;
  int node0 = (k << 9) + 2 * t;
  if (node0 < N) {
    row_start[node0] = cbase + excl;
    nchunks[node0] = pa >> 4;
    inv_deg[node0] = 1.0f / (float)(a > 1 ? a : 1);
  }
  if (node0 + 1 < N) {
    row_start[node0 + 1] = cbase + excl + pa;
    nchunks[node0 + 1] = pb >> 4;
    inv_deg[node0 + 1] = 1.0f / (float)(b > 1 ? b : 1);
  }
  __syncthreads();
  for (int i = base + t; i < end; i += 256) {
    uint p = part[i];
    int pos = atomicAdd(&cnt[p & 511u], 1);
    csr_pad[cbase + pos] = (int)(p >> 9);
  }
  // pad fill with sentinel N (zero row); disjoint from sort targets, no sync needed
  for (int i = a; i < pa; ++i) csr_pad[cbase + excl + i] = N;
  for (int i = b; i < pb; ++i) csr_pad[cbase + excl + pa + i] = N;
}

// ---------- mean aggregation: 16-lane groups, 16 gathers in flight, idx prefetch ----
__global__ __launch_bounds__(256, 4) void k_aggregate(
    const ushort* __restrict__ hb, const int* __restrict__ row_start,
    const int* __restrict__ nchunks, const float* __restrict__ inv_deg,
    const int* __restrict__ csr_pad, ushort* __restrict__ mb, int N) {
  const uint4* __restrict__ hb4 = reinterpret_cast<const uint4*>(hb);
  int wave = threadIdx.x >> 6, lane = threadIdx.x & 63;
  int g = lane >> 4, l16 = lane & 15;
  int node = blockIdx.x * 16 + wave * 4 + g;
  int rs = 0, nch = 0;
  if (node < N) { rs = row_start[node]; nch = nchunks[node]; }
  float ax[8];
#pragma unroll
  for (int j = 0; j < 8; ++j) ax[j] = 0.f;

  int idx_next = csr_pad[rs + l16];  // safe: region exists even if nch==0 (slack)
  for (int c = 0; c < nch; ++c) {
    int nidx = idx_next;
    idx_next = csr_pad[rs + ((c + 1) << 4) + l16];  // unconditional prefetch (slack-padded)
    uint4 w[16];
#pragma unroll
    for (int i = 0; i < 16; ++i) {
      int s = __shfl(nidx, (g << 4) + i);
      w[i] = hb4[(size_t)s * 16 + l16];
    }
#pragma unroll
    for (int i = 0; i < 16; ++i) {
      ax[0] += bf2f(w[i].x & 0xffffu); ax[1] += bf2f(w[i].x >> 16);
      ax[2] += bf2f(w[i].y & 0xffffu); ax[3] += bf2f(w[i].y >> 16);
      ax[4] += bf2f(w[i].z & 0xffffu); ax[5] += bf2f(w[i].z >> 16);
      ax[6] += bf2f(w[i].w & 0xffffu); ax[7] += bf2f(w[i].w >> 16);
    }
  }
  if (node < N) {
    float sc = inv_deg[node];
    uint4 o;
    o.x = pack2(ax[0] * sc, ax[1] * sc);
    o.y = pack2(ax[2] * sc, ax[3] * sc);
    o.z = pack2(ax[4] * sc, ax[5] * sc);
    o.w = pack2(ax[6] * sc, ax[7] * sc);
    reinterpret_cast<uint4*>(mb)[(size_t)node * 16 + l16] = o;
  }
}

// ---------- fused GEMM (K=256: [mean|h]) + bias + LayerNorm + ReLU ----------
// No LDS: B fragments read directly from global (identical across blocks -> L1/L2-hot).
__global__ __launch_bounds__(256, 4) void k_gemm_ln(
    const ushort* __restrict__ Amean, const ushort* __restrict__ Ah,
    const ushort* __restrict__ Wsw_l, const float* __restrict__ bl,
    const float* __restrict__ g, const float* __restrict__ be,
    ushort* __restrict__ out_b, float* __restrict__ out_f, int N) {
  int t = threadIdx.x;
  int wave = t >> 6, lane = t & 63;
  int m = lane & 15;
  int koff = (lane >> 4) * 8;
  size_t row0 = (size_t)(blockIdx.x * 128 + wave * 32 + m);
  const bf16x8* __restrict__ Wg = reinterpret_cast<const bf16x8*>(Wsw_l);

  floatx4 acc[2][8];
#pragma unroll
  for (int ti = 0; ti < 2; ++ti)
#pragma unroll
    for (int jt = 0; jt < 8; ++jt) acc[ti][jt] = (floatx4){0.f, 0.f, 0.f, 0.f};

#pragma unroll
  for (int kb = 0; kb < 8; ++kb) {
    const ushort* Asrc = (kb < 4) ? Amean : Ah;
    int ke = (kb & 3) * 32 + koff;
    bf16x8 a0 = *reinterpret_cast<const bf16x8*>(Asrc + row0 * 128 + ke);
    bf16x8 a1 = *reinterpret_cast<const bf16x8*>(Asrc + (row0 + 16) * 128 + ke);
#pragma unroll
    for (int jt = 0; jt < 8; ++jt) {
      bf16x8 b = Wg[(kb * 8 + jt) * 64 + lane];
      acc[0][jt] = __builtin_amdgcn_mfma_f32_16x16x32_bf16(a0, b, acc[0][jt], 0, 0, 0);
      acc[1][jt] = __builtin_amdgcn_mfma_f32_16x16x32_bf16(a1, b, acc[1][jt], 0, 0, 0);
    }
  }

  float blv[8], gv[8], bev[8];
#pragma unroll
  for (int jt = 0; jt < 8; ++jt) {
    int c = jt * 16 + m;
    blv[jt] = bl[c]; gv[jt] = g[c]; bev[jt] = be[c];
  }
#pragma unroll
  for (int ti = 0; ti < 2; ++ti) {
    float s[4] = {0, 0, 0, 0}, q[4] = {0, 0, 0, 0};
#pragma unroll
    for (int jt = 0; jt < 8; ++jt) {
#pragma unroll
      for (int r = 0; r < 4; ++r) {
        float v = acc[ti][jt][r] + blv[jt];
        acc[ti][jt][r] = v;
        s[r] += v; q[r] += v * v;
      }
    }
#pragma unroll
    for (int off = 1; off < 16; off <<= 1) {
#pragma unroll
      for (int r = 0; r < 4; ++r) {
        s[r] += __shfl_xor(s[r], off);
        q[r] += __shfl_xor(q[r], off);
      }
    }
    int rowbase = blockIdx.x * 128 + wave * 32 + ti * 16 + (lane >> 4) * 4;
#pragma unroll
    for (int r = 0; r < 4; ++r) {
      int row = rowbase + r;
      if (row < N) {
        float mu = s[r] * 0.0078125f;
        float var = q[r] * 0.0078125f - mu * mu;
        float rstd = rsqrtf(var + 1e-5f);
#pragma unroll
        for (int jt = 0; jt < 8; ++jt) {
          float y = (acc[ti][jt][r] - mu) * rstd * gv[jt] + bev[jt];
          y = fmaxf(y, 0.f);
          int c = jt * 16 + m;
          if (out_f) out_f[(size_t)row * 128 + c] = y;
          else out_b[(size_t)row * 128 + c] = f2bf(y);
        }
      }
    }
  }
}

extern "C" void kernel_launch(void* const* d_in, const int* in_sizes, int n_in,
                              void* d_out, int out_size, void* d_ws, size_t ws_size,
                              hipStream_t stream) {
  const float* x   = (const float*)d_in[0];
  const int*   ei  = (const int*)d_in[1];
  const float* Wl0 = (const float*)d_in[2];
  const float* bl0 = (const float*)d_in[3];
  const float* Wr0 = (const float*)d_in[4];
  const float* g0  = (const float*)d_in[5];
  const float* be0 = (const float*)d_in[6];
  const float* Wl  = (const float*)d_in[7];
  const float* bls = (const float*)d_in[8];
  const float* Wr  = (const float*)d_in[9];
  const float* gs  = (const float*)d_in[10];
  const float* bes = (const float*)d_in[11];

  int N = in_sizes[0] / 128;
  int E = in_sizes[1] / 2;
  int Np = (N + 127) & ~127;
  int nbuck = (N + NPB - 1) / NPB;
  const int* srcv = ei;
  const int* dstv = ei + E;

  char* p = (char*)d_ws;
  auto alloc = [&](size_t bytes) {
    char* r = p;
    p += (bytes + 255) & ~(size_t)255;
    return r;
  };
  ushort* xb  = (ushort*)alloc((size_t)Np * 128 * 2);
  ushort* hb  = (ushort*)alloc((size_t)Np * 128 * 2);
  ushort* mb  = (ushort*)alloc((size_t)Np * 128 * 2);
  ushort* Wsw = (ushort*)alloc((size_t)3 * 64 * 64 * 8 * 2);
  int*   cntm      = (int*)alloc((size_t)nbuck * PART_BLOCKS * 4);
  int*   offsets   = (int*)alloc((size_t)nbuck * PART_BLOCKS * 4);
  int*   blocksums = (int*)alloc(8192);
  int*   row_start = (int*)alloc((size_t)N * 4);
  int*   nchunks   = (int*)alloc((size_t)N * 4);
  float* inv_deg   = (float*)alloc((size_t)N * 4);
  uint*  part      = (uint*)alloc((size_t)E * 4);
  int*   csr_pad   = (int*)alloc(((size_t)E + (size_t)nbuck * 8192 + 256) * 4);

  // zero the sentinel row (index N) of both gather sources
  hipMemsetAsync(xb + (size_t)N * 128, 0, 256, stream);
  hipMemsetAsync(hb + (size_t)N * 128, 0, 256, stream);

  // CSR build (bucket radix, all atomics in LDS)
  int nscan = nbuck * PART_BLOCKS;
  int nScanBlocks = (nscan + 1023) / 1024;
  k_hist<<<PART_BLOCKS, 256, 0, stream>>>(dstv, cntm, E, nbuck);
  k_scan_a<<<nScanBlocks, 256, 0, stream>>>(cntm, cntm, blocksums, nscan);
  k_scan_b<<<1, 256, 0, stream>>>(blocksums, nScanBlocks);
  k_scan_apply<<<(nscan + 255) / 256, 256, 0, stream>>>(cntm, blocksums, offsets, nscan);
  k_partition<<<PART_BLOCKS, 256, 0, stream>>>(srcv, dstv, offsets, part, E, nbuck);
  k_build<<<nbuck, 256, 0, stream>>>(part, offsets, row_start, nchunks, inv_deg, csr_pad,
                                     E, N, nbuck);

  { int n4 = N * 32; k_cast_bf16<<<(n4 + 255) / 256, 256, 0, stream>>>(x, xb, n4); }
  k_swizzle_w<<<48, 256, 0, stream>>>(Wl0, Wr0, Wl, Wr, Wsw);

  dim3 aggGrid((N + 15) / 16), gemmGrid(Np / 128);
  // layer 0
  k_aggregate<<<aggGrid, 256, 0, stream>>>(xb, row_start, nchunks, inv_deg, csr_pad, mb, N);
  k_gemm_ln<<<gemmGrid, 256, 0, stream>>>(mb, xb, Wsw + 0 * 32768, bl0, g0, be0,
                                          hb, nullptr, N);
  // layer 1
  k_aggregate<<<aggGrid, 256, 0, stream>>>(hb, row_start, nchunks, inv_deg, csr_pad, mb, N);
  k_gemm_ln<<<gemmGrid, 256, 0, stream>>>(mb, hb, Wsw + 1 * 32768, bls + 0, gs + 0, bes + 0,
                                          xb, nullptr, N);
  // layer 2 (writes f32 directly to d_out)
  k_aggregate<<<aggGrid, 256, 0, stream>>>(xb, row_start, nchunks, inv_deg, csr_pad, mb, N);
  k_gemm_ln<<<gemmGrid, 256, 0, stream>>>(mb, xb, Wsw + 2 * 32768, bls + 128, gs + 128,
                                          bes + 128, nullptr, (float*)d_out, N);
}

// Round 5
// 452.887 us; speedup vs baseline: 1.6353x; 1.0308x over previous
//
#include <hip/hip_runtime.h>
#include <stdint.h>

typedef unsigned int uint;
typedef unsigned short ushort;

typedef float floatx4 __attribute__((ext_vector_type(4)));
typedef __bf16 bf16x8 __attribute__((ext_vector_type(8)));

#define NPB 512          // nodes per bucket (dst >> 9)
#define PART_BLOCKS 256  // blocks in hist/partition passes

// ---------- bf16 helpers (RNE, bit-level) ----------
__device__ __forceinline__ ushort f2bf(float f) {
  uint u = __float_as_uint(f);
  u += 0x7fffu + ((u >> 16) & 1u);
  return (ushort)(u >> 16);
}
__device__ __forceinline__ float bf2f(uint bits) {
  return __uint_as_float(bits << 16);
}
__device__ __forceinline__ uint pack2(float a, float b) {
  return (uint)f2bf(a) | ((uint)f2bf(b) << 16);
}

// ---------- fused prep: cast x->bf16, swizzle W, zero sentinel rows ----------
__global__ void k_prep(const float* __restrict__ x, ushort* __restrict__ xb,
                       ushort* __restrict__ hb,
                       const float* __restrict__ Wl0, const float* __restrict__ Wr0,
                       const float* __restrict__ Wl, const float* __restrict__ Wr,
                       ushort* __restrict__ Wsw, int n4, int nCast, int N) {
  int b = blockIdx.x, tid = threadIdx.x;
  if (b < nCast) {                       // cast part
    int i = b * 256 + tid;
    if (i >= n4) return;
    float4 v = reinterpret_cast<const float4*>(x)[i];
    ushort4 o;
    o.x = f2bf(v.x); o.y = f2bf(v.y); o.z = f2bf(v.z); o.w = f2bf(v.w);
    reinterpret_cast<ushort4*>(xb)[i] = o;
  } else if (b < nCast + 48) {           // W swizzle part
    int t = (b - nCast) * 256 + tid;
    if (t >= 3 * 64 * 64) return;
    int lane = t & 63;
    int blk = (t >> 6) & 63;
    int l = t >> 12;
    int kb = blk >> 3, jt = blk & 7;
    int col = jt * 16 + (lane & 15);
    ushort tmp[8];
#pragma unroll
    for (int j = 0; j < 8; ++j) {
      int k = kb * 32 + (lane >> 4) * 8 + j;
      float v;
      if (k < 128) {
        v = (l == 0) ? Wl0[k * 128 + col] : Wl[(l - 1) * 16384 + k * 128 + col];
      } else {
        int k2 = k - 128;
        v = (l == 0) ? Wr0[k2 * 128 + col] : Wr[(l - 1) * 16384 + k2 * 128 + col];
      }
      tmp[j] = f2bf(v);
    }
    reinterpret_cast<uint4*>(Wsw)[t] = *reinterpret_cast<uint4*>(tmp);
  } else {                               // sentinel row N of xb and hb -> 0
    uint* xr = reinterpret_cast<uint*>(xb + (size_t)N * 128);
    uint* hr = reinterpret_cast<uint*>(hb + (size_t)N * 128);
    if (tid < 64) xr[tid] = 0;
    else if (tid < 128) hr[tid - 64] = 0;
  }
}

// ---------- bucket histogram: cnt[bucket * PART_BLOCKS + block] ----------
__global__ __launch_bounds__(256) void k_hist(const int* __restrict__ dst,
                                              int* __restrict__ cnt, int E, int nbuck) {
  __shared__ int lc[256];
  int t = threadIdx.x;
  lc[t] = 0;
  __syncthreads();
  int per = (E + PART_BLOCKS - 1) / PART_BLOCKS;
  int s = blockIdx.x * per, e = min(E, s + per);
  for (int i = s + t; i < e; i += 256) atomicAdd(&lc[dst[i] >> 9], 1);
  __syncthreads();
  if (t < nbuck) cnt[t * PART_BLOCKS + blockIdx.x] = lc[t];
}

// ---------- scan pass A (in-place capable) ----------
__global__ void k_scan_a(const int* __restrict__ in, int* __restrict__ partial,
                         int* __restrict__ blocksums, int n) {
  __shared__ int sm[256];
  int t = threadIdx.x;
  int base = blockIdx.x * 1024 + t * 4;
  int v0 = 0, v1 = 0, v2 = 0, v3 = 0;
  if (base + 0 < n) v0 = in[base + 0];
  if (base + 1 < n) v1 = in[base + 1];
  if (base + 2 < n) v2 = in[base + 2];
  if (base + 3 < n) v3 = in[base + 3];
  int mysum = v0 + v1 + v2 + v3;
  sm[t] = mysum;
  __syncthreads();
  for (int off = 1; off < 256; off <<= 1) {
    int x = (t >= off) ? sm[t - off] : 0;
    __syncthreads();
    sm[t] += x;
    __syncthreads();
  }
  int excl = sm[t] - mysum;
  if (t == 255) blocksums[blockIdx.x] = sm[255];
  if (base + 0 < n) partial[base + 0] = excl;
  if (base + 1 < n) partial[base + 1] = excl + v0;
  if (base + 2 < n) partial[base + 2] = excl + v0 + v1;
  if (base + 3 < n) partial[base + 3] = excl + v0 + v1 + v2;
}

// ---------- parallel single-block scan of block sums (nb <= 256) ----------
__global__ void k_scan_b(int* blocksums, int nb) {
  __shared__ int sm[256];
  int t = threadIdx.x;
  int v = (t < nb) ? blocksums[t] : 0;
  sm[t] = v;
  __syncthreads();
  for (int off = 1; off < 256; off <<= 1) {
    int x = (t >= off) ? sm[t - off] : 0;
    __syncthreads();
    sm[t] += x;
    __syncthreads();
  }
  if (t < nb) blocksums[t] = sm[t] - v;  // exclusive
}

// ---------- partition edges into bucket-major packed array ----------
__global__ __launch_bounds__(256) void k_partition(const int* __restrict__ src,
                                                   const int* __restrict__ dst,
                                                   const int* __restrict__ cntm,
                                                   const int* __restrict__ blocksums,
                                                   uint* __restrict__ part, int E, int nbuck) {
  __shared__ int cur[256];
  int t = threadIdx.x;
  if (t < nbuck) {
    int idx = t * PART_BLOCKS + blockIdx.x;
    cur[t] = cntm[idx] + blocksums[idx >> 10];
  }
  __syncthreads();
  int per = (E + PART_BLOCKS - 1) / PART_BLOCKS;
  int s = blockIdx.x * per, e = min(E, s + per);
  for (int i = s + t; i < e; i += 256) {
    int d = dst[i];
    int k = d >> 9;
    int pos = atomicAdd(&cur[k], 1);
    part[pos] = ((uint)src[i] << 9) | (uint)(d & 511);
  }
}

// ---------- per-bucket LDS counting sort -> PADDED csr (pad to x16 with sentinel N) ----
__global__ __launch_bounds__(256) void k_build(const uint* __restrict__ part,
                                               const int* __restrict__ cntm,
                                               const int* __restrict__ blocksums,
                                               int* __restrict__ row_start,
                                               int* __restrict__ nchunks,
                                               float* __restrict__ inv_deg,
                                               int* __restrict__ csr_pad,
                                               int E, int N, int nbuck) {
  int k = blockIdx.x;
  __shared__ int cnt[512];
  __shared__ int sm[256];
  __shared__ int rng[2];
  int t = threadIdx.x;
  if (t == 0) {
    int i0 = k * PART_BLOCKS;
    rng[0] = cntm[i0] + blocksums[i0 >> 10];
    int i1 = (k + 1) * PART_BLOCKS;
    rng[1] = (k + 1 < nbuck) ? cntm[i1] + blocksums[i1 >> 10] : E;
  }
  cnt[t] = 0; cnt[t + 256] = 0;
  __syncthreads();
  int base = rng[0], end = rng[1];
  int cbase = base + k * 8192;  // padded-array base (per-bucket slack = 8192 >= 15*512)
  for (int i = base + t; i < end; i += 256) atomicAdd(&cnt[part[i] & 511u], 1);
  __syncthreads();
  int a = cnt[2 * t], b = cnt[2 * t + 1];
  int pa = (a + 15) & ~15, pb = (b + 15) & ~15;
  int psum = pa + pb;
  sm[t] = psum;
  __syncthreads();
  for (int off = 1; off < 256; off <<= 1) {
    int x = (t >= off) ? sm[t - off] : 0;
    __syncthreads();
    sm[t] += x;
    __syncthreads();
  }
  int excl = sm[t] - psum;
  cnt[2 * t] = excl;
  cnt[2 * t + 1] = excl + pa;
  int node0 = (k << 9) + 2 * t;
  if (node0 < N) {
    row_start[node0] = cbase + excl;
    nchunks[node0] = pa >> 4;
    inv_deg[node0] = 1.0f / (float)(a > 1 ? a : 1);
  }
  if (node0 + 1 < N) {
    row_start[node0 + 1] = cbase + excl + pa;
    nchunks[node0 + 1] = pb >> 4;
    inv_deg[node0 + 1] = 1.0f / (float)(b > 1 ? b : 1);
  }
  __syncthreads();
  for (int i = base + t; i < end; i += 256) {
    uint p = part[i];
    int pos = atomicAdd(&cnt[p & 511u], 1);
    csr_pad[cbase + pos] = (int)(p >> 9);
  }
  // pad fill with sentinel N (zero row); disjoint from sort targets, no sync needed
  for (int i = a; i < pa; ++i) csr_pad[cbase + excl + i] = N;
  for (int i = b; i < pb; ++i) csr_pad[cbase + excl + pa + i] = N;
}

// ---------- fused layer: aggregate 128 nodes -> LDS A-frags -> GEMM+bias+LN+ReLU ----
// LDS mean-tile layout (16B chunks): idx16(rt,kbl,kg,m) = rt*256 + kbl*64 + kg*16
//   + (m ^ (kbl*4+kg)); XOR keeps both ds_write scatter and ds_read at baseline banks.
__global__ __launch_bounds__(256, 4) void k_layer(
    const ushort* __restrict__ src, const int* __restrict__ row_start,
    const int* __restrict__ nchunks, const float* __restrict__ inv_deg,
    const int* __restrict__ csr_pad, const ushort* __restrict__ Wsw_l,
    const float* __restrict__ bl, const float* __restrict__ g,
    const float* __restrict__ be, ushort* __restrict__ out_b,
    float* __restrict__ out_f, int N) {
  __shared__ ushort lA[16384];  // 32 KB
  const uint4* __restrict__ hb4 = reinterpret_cast<const uint4*>(src);
  int t = threadIdx.x, wave = t >> 6, lane = t & 63;
  int g16 = lane >> 4, l16 = lane & 15;
  int G = wave * 4 + g16;  // 16 groups; group handles 8 consecutive nodes

  // ---- phase 1: mean aggregation (16 gathers in flight per group) ----
  for (int i = 0; i < 8; ++i) {
    int nb = G * 8 + i;
    int node = blockIdx.x * 128 + nb;
    int rs = 0, nch = 0;
    float sc = 0.f;
    if (node < N) { rs = row_start[node]; nch = nchunks[node]; sc = inv_deg[node]; }
    float ax[8];
#pragma unroll
    for (int j = 0; j < 8; ++j) ax[j] = 0.f;
    int idx_next = csr_pad[rs + l16];
    for (int c = 0; c < nch; ++c) {
      int nidx = idx_next;
      idx_next = csr_pad[rs + ((c + 1) << 4) + l16];  // slack-padded, always valid
      uint4 w[16];
#pragma unroll
      for (int u = 0; u < 16; ++u) {
        int s = __shfl(nidx, (g16 << 4) + u);
        w[u] = hb4[(size_t)s * 16 + l16];
      }
#pragma unroll
      for (int u = 0; u < 16; ++u) {
        ax[0] += bf2f(w[u].x & 0xffffu); ax[1] += bf2f(w[u].x >> 16);
        ax[2] += bf2f(w[u].y & 0xffffu); ax[3] += bf2f(w[u].y >> 16);
        ax[4] += bf2f(w[u].z & 0xffffu); ax[5] += bf2f(w[u].z >> 16);
        ax[6] += bf2f(w[u].w & 0xffffu); ax[7] += bf2f(w[u].w >> 16);
      }
    }
    uint4 o;
    o.x = pack2(ax[0] * sc, ax[1] * sc);
    o.y = pack2(ax[2] * sc, ax[3] * sc);
    o.z = pack2(ax[4] * sc, ax[5] * sc);
    o.w = pack2(ax[6] * sc, ax[7] * sc);
    // lane l16 holds k-chunk l16 of node nb: kbl=l16>>2, kg=l16&3
    int idx16 = ((nb >> 4) << 8) + ((l16 >> 2) << 6) + ((l16 & 3) << 4) + ((nb & 15) ^ l16);
    *reinterpret_cast<uint4*>(&lA[idx16 * 8]) = o;
  }
  __syncthreads();

  // ---- phase 2: GEMM (K=256 = [mean|h]) + bias + LayerNorm + ReLU ----
  int m = lane & 15;
  int kgp = lane >> 4;
  int koff = kgp * 8;
  size_t row0 = (size_t)(blockIdx.x * 128 + wave * 32 + m);
  const bf16x8* __restrict__ Wg = reinterpret_cast<const bf16x8*>(Wsw_l);

  floatx4 acc[2][8];
#pragma unroll
  for (int ti = 0; ti < 2; ++ti)
#pragma unroll
    for (int jt = 0; jt < 8; ++jt) acc[ti][jt] = (floatx4){0.f, 0.f, 0.f, 0.f};

#pragma unroll
  for (int kb = 0; kb < 8; ++kb) {
    bf16x8 a0, a1;
    if (kb < 4) {  // mean half from LDS fragments
      int i0 = ((wave * 2) << 8) + (kb << 6) + (kgp << 4) + (m ^ (kb * 4 + kgp));
      a0 = *reinterpret_cast<const bf16x8*>(&lA[i0 * 8]);
      a1 = *reinterpret_cast<const bf16x8*>(&lA[(i0 + 256) * 8]);
    } else {       // h half direct from global
      int ke = (kb & 3) * 32 + koff;
      a0 = *reinterpret_cast<const bf16x8*>(src + row0 * 128 + ke);
      a1 = *reinterpret_cast<const bf16x8*>(src + (row0 + 16) * 128 + ke);
    }
#pragma unroll
    for (int jt = 0; jt < 8; ++jt) {
      bf16x8 b = Wg[(kb * 8 + jt) * 64 + lane];
      acc[0][jt] = __builtin_amdgcn_mfma_f32_16x16x32_bf16(a0, b, acc[0][jt], 0, 0, 0);
      acc[1][jt] = __builtin_amdgcn_mfma_f32_16x16x32_bf16(a1, b, acc[1][jt], 0, 0, 0);
    }
  }

  float blv[8], gv[8], bev[8];
#pragma unroll
  for (int jt = 0; jt < 8; ++jt) {
    int c = jt * 16 + m;
    blv[jt] = bl[c]; gv[jt] = g[c]; bev[jt] = be[c];
  }
#pragma unroll
  for (int ti = 0; ti < 2; ++ti) {
    float s[4] = {0, 0, 0, 0}, q[4] = {0, 0, 0, 0};
#pragma unroll
    for (int jt = 0; jt < 8; ++jt) {
#pragma unroll
      for (int r = 0; r < 4; ++r) {
        float v = acc[ti][jt][r] + blv[jt];
        acc[ti][jt][r] = v;
        s[r] += v; q[r] += v * v;
      }
    }
#pragma unroll
    for (int off = 1; off < 16; off <<= 1) {
#pragma unroll
      for (int r = 0; r < 4; ++r) {
        s[r] += __shfl_xor(s[r], off);
        q[r] += __shfl_xor(q[r], off);
      }
    }
    int rowbase = blockIdx.x * 128 + wave * 32 + ti * 16 + (lane >> 4) * 4;
#pragma unroll
    for (int r = 0; r < 4; ++r) {
      int row = rowbase + r;
      if (row < N) {
        float mu = s[r] * 0.0078125f;
        float var = q[r] * 0.0078125f - mu * mu;
        float rstd = rsqrtf(var + 1e-5f);
#pragma unroll
        for (int jt = 0; jt < 8; ++jt) {
          float y = (acc[ti][jt][r] - mu) * rstd * gv[jt] + bev[jt];
          y = fmaxf(y, 0.f);
          int c = jt * 16 + m;
          if (out_f) out_f[(size_t)row * 128 + c] = y;
          else out_b[(size_t)row * 128 + c] = f2bf(y);
        }
      }
    }
  }
}

extern "C" void kernel_launch(void* const* d_in, const int* in_sizes, int n_in,
                              void* d_out, int out_size, void* d_ws, size_t ws_size,
                              hipStream_t stream) {
  const float* x   = (const float*)d_in[0];
  const int*   ei  = (const int*)d_in[1];
  const float* Wl0 = (const float*)d_in[2];
  const float* bl0 = (const float*)d_in[3];
  const float* Wr0 = (const float*)d_in[4];
  const float* g0  = (const float*)d_in[5];
  const float* be0 = (const float*)d_in[6];
  const float* Wl  = (const float*)d_in[7];
  const float* bls = (const float*)d_in[8];
  const float* Wr  = (const float*)d_in[9];
  const float* gs  = (const float*)d_in[10];
  const float* bes = (const float*)d_in[11];

  int N = in_sizes[0] / 128;
  int E = in_sizes[1] / 2;
  int Np = (N + 127) & ~127;
  int nbuck = (N + NPB - 1) / NPB;
  const int* srcv = ei;
  const int* dstv = ei + E;

  char* p = (char*)d_ws;
  auto alloc = [&](size_t bytes) {
    char* r = p;
    p += (bytes + 255) & ~(size_t)255;
    return r;
  };
  ushort* xb  = (ushort*)alloc((size_t)(Np + 16) * 128 * 2);
  ushort* hb  = (ushort*)alloc((size_t)(Np + 16) * 128 * 2);
  ushort* Wsw = (ushort*)alloc((size_t)3 * 64 * 64 * 8 * 2);
  int*   cntm      = (int*)alloc((size_t)nbuck * PART_BLOCKS * 4);
  int*   blocksums = (int*)alloc(8192);
  int*   row_start = (int*)alloc((size_t)N * 4);
  int*   nchunks   = (int*)alloc((size_t)N * 4);
  float* inv_deg   = (float*)alloc((size_t)N * 4);
  uint*  part      = (uint*)alloc((size_t)E * 4);
  int*   csr_pad   = (int*)alloc(((size_t)E + (size_t)nbuck * 8192 + 256) * 4);

  // CSR build (bucket radix, all atomics in LDS)
  int nscan = nbuck * PART_BLOCKS;
  int nScanBlocks = (nscan + 1023) / 1024;
  k_hist<<<PART_BLOCKS, 256, 0, stream>>>(dstv, cntm, E, nbuck);
  k_scan_a<<<nScanBlocks, 256, 0, stream>>>(cntm, cntm, blocksums, nscan);
  k_scan_b<<<1, 256, 0, stream>>>(blocksums, nScanBlocks);
  k_partition<<<PART_BLOCKS, 256, 0, stream>>>(srcv, dstv, cntm, blocksums, part, E, nbuck);
  k_build<<<nbuck, 256, 0, stream>>>(part, cntm, blocksums, row_start, nchunks, inv_deg,
                                     csr_pad, E, N, nbuck);

  int n4 = N * 32;
  int nCast = (n4 + 255) / 256;
  k_prep<<<nCast + 49, 256, 0, stream>>>(x, xb, hb, Wl0, Wr0, Wl, Wr, Wsw, n4, nCast, N);

  dim3 grid(Np / 128);
  // layer 0: src=xb -> out hb (bf16)
  k_layer<<<grid, 256, 0, stream>>>(xb, row_start, nchunks, inv_deg, csr_pad,
                                    Wsw + 0 * 32768, bl0, g0, be0, hb, nullptr, N);
  // layer 1: src=hb -> out xb (bf16)
  k_layer<<<grid, 256, 0, stream>>>(hb, row_start, nchunks, inv_deg, csr_pad,
                                    Wsw + 1 * 32768, bls + 0, gs + 0, bes + 0,
                                    xb, nullptr, N);
  // layer 2: src=xb -> out d_out (f32)
  k_layer<<<grid, 256, 0, stream>>>(xb, row_start, nchunks, inv_deg, csr_pad,
                                    Wsw + 2 * 32768, bls + 128, gs + 128, bes + 128,
                                    nullptr, (float*)d_out, N);
}